// Round 1
// baseline (708.044 us; speedup 1.0000x reference)
//
#include <hip/hip_runtime.h>
#include <cstdint>
#include <cstddef>

// ---------------- types / helpers ----------------
typedef __attribute__((ext_vector_type(8))) __bf16 bf16x8;
typedef __attribute__((ext_vector_type(4))) float f32x4;

__device__ __forceinline__ unsigned short f2b(float x) {
    uint32_t u = __float_as_uint(x);
    u += 0x7FFFu + ((u >> 16) & 1u);   // RNE
    return (unsigned short)(u >> 16);
}
__device__ __forceinline__ float b2f(unsigned short h) {
    return __uint_as_float(((uint32_t)h) << 16);
}

#define L_SEQ 512
#define N_AA 21
#define DDIM 128
#define NCOL 2688        // 21*128
#define NSEQ 512         // 256 + 256
#define TSTRIDE 448      // padded 441

// ---------------- kernel 1: repack X int32 -> u8, combined [512][512] ----------------
__global__ __launch_bounds__(256) void repack_kernel(const int* X1, const int* X2, uint8_t* X8) {
    int e = blockIdx.x * 256 + threadIdx.x;   // 262144 total
    if (e < 131072) X8[e] = (uint8_t)X1[e];
    else            X8[e] = (uint8_t)X2[e - 131072];
}

// ---------------- kernel 2: build w = sigmoid(wm), fp32 + bf16 ----------------
__global__ __launch_bounds__(256) void w_build_kernel(const float* wp, float* w32, unsigned short* wb16) {
    int e = blockIdx.x * 256 + threadIdx.x;   // 262144 = 512*512
    int p = e >> 9, q = e & 511;
    float x = 0.0f;
    if (p > q)      x = wp[p * (p - 1) / 2 + q];
    else if (p < q) x = wp[q * (q - 1) / 2 + p];
    float s = 1.0f / (1.0f + expf(-x));
    w32[e] = s;
    wb16[e] = f2b(s);
}

// ---------------- kernel 3: E[n,:] = b + sum_l W[l*21 + X[n,l], :] ----------------
// grid (21 col-tiles of 128, 32 n-groups of 16), 256 threads
__global__ __launch_bounds__(256) void e_kernel(const uint8_t* X8, const float* W, const float* bvec, float* E) {
    __shared__ uint8_t Xs[16 * 512];
    int t = threadIdx.x;
    int c0 = blockIdx.x * 128;
    int n0 = blockIdx.y * 16;
    {
        const uint32_t* src = (const uint32_t*)(X8 + (size_t)n0 * 512);
        uint32_t* dst = (uint32_t*)Xs;
        for (int e = t; e < 2048; e += 256) dst[e] = src[e];
    }
    __syncthreads();
    int c  = c0 + (t & 127);
    int nh = t >> 7;   // 0/1 -> which 8 sequences
    float acc[8];
#pragma unroll
    for (int k = 0; k < 8; ++k) acc[k] = 0.f;
    for (int l = 0; l < L_SEQ; ++l) {
        const float* Wl = W + (size_t)l * (N_AA * NCOL) + c;
#pragma unroll
        for (int k = 0; k < 8; ++k) {
            int idx = Xs[(nh * 8 + k) * 512 + l];
            idx = __builtin_amdgcn_readfirstlane(idx);   // wave-uniform
            acc[k] += Wl[(size_t)idx * NCOL];
        }
    }
    float bv = bvec[c];
#pragma unroll
    for (int k = 0; k < 8; ++k)
        E[(size_t)(n0 + nh * 8 + k) * NCOL + c] = acc[k] + bv;
}

// ---------------- kernel 4: T[n] = E[n] @ E[n]^T  (21x21) ----------------
__global__ __launch_bounds__(256) void t_kernel(const float* E, float* T) {
    __shared__ float Es[NCOL];
    int t = threadIdx.x, n = blockIdx.x;
    for (int e = t; e < NCOL; e += 256) Es[e] = E[(size_t)n * NCOL + e];
    __syncthreads();
    for (int e = t; e < 441; e += 256) {
        int r = e / 21, c = e - r * 21;
        const float* ar = &Es[r * DDIM];
        const float* br = &Es[c * DDIM];
        float s = 0.f;
#pragma unroll 4
        for (int d = 0; d < DDIM; ++d) s += ar[d] * br[d];
        T[(size_t)n * TSTRIDE + e] = s;
    }
}

// ---------------- kernel 5: kinv[n] = 1/sqrt(d^T w d), d_l = T[n][x_l, x_l] ----------------
__global__ __launch_bounds__(256) void k_kernel(const uint8_t* X8, const float* T, const float* w32, float* kinv) {
    __shared__ __align__(16) float dvec[512];
    __shared__ float Td[21];
    __shared__ float red[256];
    int t = threadIdx.x, n = blockIdx.x;
    if (t < 21) Td[t] = T[(size_t)n * TSTRIDE + t * 21 + t];
    __syncthreads();
    for (int l = t; l < 512; l += 256) dvec[l] = Td[X8[(size_t)n * 512 + l]];
    __syncthreads();
    float partial = 0.f;
    for (int p = t; p < 512; p += 256) {
        const float4* wr4 = (const float4*)(w32 + (size_t)p * 512);
        const float4* dv4 = (const float4*)dvec;
        float dot = 0.f;
        for (int q = 0; q < 128; ++q) {
            float4 wv = wr4[q];
            float4 dv = dv4[q];
            dot += wv.x * dv.x + wv.y * dv.y + wv.z * dv.z + wv.w * dv.w;
        }
        partial += dvec[p] * dot;
    }
    red[t] = partial;
    __syncthreads();
    for (int s = 128; s > 0; s >>= 1) {
        if (t < s) red[t] += red[t + s];
        __syncthreads();
    }
    if (t == 0) kinv[n] = 1.0f / sqrtf(red[0]);
}

// ---------------- kernel 6: main pair GEMM ----------------
// Tile: 4 i's x 8 j's = 32 pairs per block. grid (64, 32).
// S[pair][p] = bf16( 0.5*(T1[i][a,b] + T2[j][a,b]) ), a=X1[i,p], b=X2[j,p]
// Y = S @ w (MFMA 16x16x32 bf16), fused epilogue: K[pair] = sum_n Y[pair,n]*S[pair,n]
// out[i,j] = a^2 * K * kinv[i] * kinv[256+j]
__global__ __launch_bounds__(256) void k4_kernel(const uint8_t* X8, const float* T,
                                                 const unsigned short* wb16, const float* kinv,
                                                 const float* Ainp, float* out) {
    __shared__ unsigned short Sh[32 * 520];   // 33280 B, stride 520 avoids bank conflict
    __shared__ unsigned short Wt[128 * 40];   // 10240 B, [n][k] tile (w symmetric)
    __shared__ unsigned short Ts1[4 * 441];   // bf16 lookup tables
    __shared__ unsigned short Ts2[8 * 441];
    __shared__ uint8_t Xs1[4 * 512];
    __shared__ uint8_t Xs2[8 * 512];
    __shared__ float Kacc[2][32];

    int t = threadIdx.x;
    int i0 = blockIdx.x * 4;
    int j0 = blockIdx.y * 8;

    // stage X rows
    {
        const uint32_t* s1 = (const uint32_t*)(X8 + (size_t)i0 * 512);
        uint32_t* d1 = (uint32_t*)Xs1;
        for (int e = t; e < 512; e += 256) d1[e] = s1[e];
        const uint32_t* s2 = (const uint32_t*)(X8 + (size_t)(256 + j0) * 512);
        uint32_t* d2 = (uint32_t*)Xs2;
        for (int e = t; e < 1024; e += 256) d2[e] = s2[e];
    }
    // stage T tables (bf16)
    for (int e = t; e < 4 * 441; e += 256) {
        int r = e / 441, c = e - r * 441;
        Ts1[e] = f2b(T[(size_t)(i0 + r) * TSTRIDE + c]);
    }
    for (int e = t; e < 8 * 441; e += 256) {
        int r = e / 441, c = e - r * 441;
        Ts2[e] = f2b(T[(size_t)(256 + j0 + r) * TSTRIDE + c]);
    }
    if (t < 64) Kacc[t >> 5][t & 31] = 0.f;
    __syncthreads();

    // build S tile: 32 pairs x 512 positions
    for (int e = t; e < 32 * 512; e += 256) {
        int pr = e >> 9, p = e & 511;
        int ti = pr >> 3, tj = pr & 7;
        int a = Xs1[ti * 512 + p];
        int b = Xs2[tj * 512 + p];
        float v = 0.5f * (b2f(Ts1[ti * 441 + a * 21 + b]) + b2f(Ts2[tj * 441 + a * 21 + b]));
        Sh[pr * 520 + p] = f2b(v);
    }
    __syncthreads();

    int wid = t >> 6, lane = t & 63;
    int wm = (wid >> 1) * 16;   // wave's M offset (0/16)
    int wn = (wid & 1) * 64;    // wave's N offset within 128-tile (0/64)
    int lr = lane & 15, q = lane >> 4;

    for (int nt = 0; nt < 4; ++nt) {
        int n0 = nt * 128;
        f32x4 acc[4];
#pragma unroll
        for (int ni = 0; ni < 4; ++ni) acc[ni] = (f32x4){0.f, 0.f, 0.f, 0.f};

        for (int kt = 0; kt < 16; ++kt) {
            int k0 = kt * 32;
            __syncthreads();   // protect Wt from previous readers
            // stage Wt[128][32] from wb16 rows (n0..n0+127), cols (k0..k0+31)
            {
                int r = t >> 2, seg = t & 3;
                const uint4* g1 = (const uint4*)(wb16 + (size_t)(n0 + r) * 512 + k0 + seg * 8);
                *(uint4*)&Wt[r * 40 + seg * 8] = *g1;
                const uint4* g2 = (const uint4*)(wb16 + (size_t)(n0 + r + 64) * 512 + k0 + seg * 8);
                *(uint4*)&Wt[(r + 64) * 40 + seg * 8] = *g2;
            }
            __syncthreads();
            bf16x8 av = *(const bf16x8*)&Sh[(wm + lr) * 520 + k0 + q * 8];
#pragma unroll
            for (int ni = 0; ni < 4; ++ni) {
                bf16x8 bv = *(const bf16x8*)&Wt[(wn + ni * 16 + lr) * 40 + q * 8];
                acc[ni] = __builtin_amdgcn_mfma_f32_16x16x32_bf16(av, bv, acc[ni], 0, 0, 0);
            }
        }

        // fused epilogue dot for this n-tile
        float prow[4] = {0.f, 0.f, 0.f, 0.f};
#pragma unroll
        for (int ni = 0; ni < 4; ++ni) {
            int colg = n0 + wn + ni * 16 + lr;
            float sv = b2f(Sh[(wm + q * 4 + 0) * 520 + colg]);
            // note: rows differ per r; read per (r, ni)
            prow[0] += acc[ni][0] * sv;
#pragma unroll
            for (int r = 1; r < 4; ++r) {
                float sv2 = b2f(Sh[(wm + q * 4 + r) * 520 + colg]);
                prow[r] += acc[ni][r] * sv2;
            }
        }
#pragma unroll
        for (int r = 0; r < 4; ++r) {
            float v = prow[r];
            v += __shfl_xor(v, 1);
            v += __shfl_xor(v, 2);
            v += __shfl_xor(v, 4);
            v += __shfl_xor(v, 8);
            if (lr == 0) Kacc[wid & 1][wm + q * 4 + r] += v;
        }
    }
    __syncthreads();

    if (t < 32) {
        float K = Kacc[0][t] + Kacc[1][t];
        int ti = t >> 3, tj = t & 7;
        int i = i0 + ti, j = j0 + tj;
        float a0 = Ainp[0];
        out[i * 256 + j] = a0 * a0 * K * kinv[i] * kinv[256 + j];
    }
}

// ---------------- launcher ----------------
extern "C" void kernel_launch(void* const* d_in, const int* in_sizes, int n_in,
                              void* d_out, int out_size, void* d_ws, size_t ws_size,
                              hipStream_t stream) {
    const int*   X1 = (const int*)d_in[0];
    const int*   X2 = (const int*)d_in[1];
    const float* W  = (const float*)d_in[2];
    const float* b  = (const float*)d_in[3];
    const float* wp = (const float*)d_in[4];
    const float* a  = (const float*)d_in[5];
    float* out = (float*)d_out;

    char* ws = (char*)d_ws;
    float*          E    = (float*)(ws + 0);            // 512*2688*4    = 5,505,024
    float*          T    = (float*)(ws + 5505024);      // 512*448*4     =   917,504
    float*          w32  = (float*)(ws + 6422528);      // 512*512*4     = 1,048,576
    unsigned short* wb16 = (unsigned short*)(ws + 7471104); // 512*512*2 =   524,288
    float*          kinv = (float*)(ws + 7995392);      // 512*4         =     2,048
    uint8_t*        X8   = (uint8_t*)(ws + 7997440);    // 512*512       =   262,144

    repack_kernel<<<1024, 256, 0, stream>>>(X1, X2, X8);
    w_build_kernel<<<1024, 256, 0, stream>>>(wp, w32, wb16);
    e_kernel<<<dim3(21, 32), 256, 0, stream>>>(X8, W, b, E);
    t_kernel<<<512, 256, 0, stream>>>(E, T);
    k_kernel<<<512, 256, 0, stream>>>(X8, T, w32, kinv);
    k4_kernel<<<dim3(64, 32), 256, 0, stream>>>(X8, T, wb16, kinv, a, out);
}

// Round 2
// 637.567 us; speedup vs baseline: 1.1105x; 1.1105x over previous
//
#include <hip/hip_runtime.h>
#include <cstdint>
#include <cstddef>

// ---------------- types / helpers ----------------
typedef __attribute__((ext_vector_type(8))) __bf16 bf16x8;
typedef __attribute__((ext_vector_type(4))) float f32x4;
typedef __attribute__((ext_vector_type(16))) float f32x16;

__device__ __forceinline__ unsigned short f2b(float x) {
    uint32_t u = __float_as_uint(x);
    u += 0x7FFFu + ((u >> 16) & 1u);   // RNE
    return (unsigned short)(u >> 16);
}
__device__ __forceinline__ float b2f(unsigned short h) {
    return __uint_as_float(((uint32_t)h) << 16);
}

#define L_SEQ 512
#define N_AA 21
#define DDIM 128
#define NCOL 2688        // 21*128
#define NSEQ 512         // 256 + 256
#define TSTRIDE 448      // padded 441

// ---------------- kernel 1: repack X int32 -> u8, combined [512][512] ----------------
__global__ __launch_bounds__(256) void repack_kernel(const int* X1, const int* X2, uint8_t* X8) {
    int e = blockIdx.x * 256 + threadIdx.x;   // 262144 total
    if (e < 131072) X8[e] = (uint8_t)X1[e];
    else            X8[e] = (uint8_t)X2[e - 131072];
}

// ---------------- kernel 2: build w = sigmoid(wm), fp32 + bf16 ----------------
__global__ __launch_bounds__(256) void w_build_kernel(const float* wp, float* w32, unsigned short* wb16) {
    int e = blockIdx.x * 256 + threadIdx.x;   // 262144 = 512*512
    int p = e >> 9, q = e & 511;
    float x = 0.0f;
    if (p > q)      x = wp[p * (p - 1) / 2 + q];
    else if (p < q) x = wp[q * (q - 1) / 2 + p];
    float s = 1.0f / (1.0f + expf(-x));
    w32[e] = s;
    wb16[e] = f2b(s);
}

// ---------------- kernel 3a: E init with bias ----------------
__global__ __launch_bounds__(256) void e_init_kernel(const float* bvec, float* E) {
    int e = blockIdx.x * 256 + threadIdx.x;   // 512*2688 = 1376256
    int c = e % NCOL;
    E[e] = bvec[c];
}

// ---------------- kernel 3b: E[n,:] += sum_{l in chunk} W[l*21 + X[n,l], :] ----------------
// grid (21 col-tiles of 128, 32 seq-groups of 16, 4 l-chunks of 128), 256 threads.
// thread: cp = t&63 (col pair), sg = t>>6 (4 seqs each). Local fp32 acc, one
// atomicAdd per element at the end (e-init supplies bias).
__global__ __launch_bounds__(256) void e_gather_kernel(const uint8_t* X8, const float* W, float* E) {
    __shared__ uint8_t Xs[16 * 128];
    int t = threadIdx.x;
    int c0 = blockIdx.x * 128;
    int n0 = blockIdx.y * 16;
    int l0 = blockIdx.z * 128;
    {
        int row = t >> 4, seg = t & 15;
        *(uint64_t*)&Xs[row * 128 + seg * 8] =
            *(const uint64_t*)&X8[(size_t)(n0 + row) * 512 + l0 + seg * 8];
    }
    __syncthreads();
    int sg = t >> 6, cp = t & 63;
    int c = c0 + cp * 2;
    float acc[4][2];
#pragma unroll
    for (int s = 0; s < 4; ++s) { acc[s][0] = 0.f; acc[s][1] = 0.f; }

    for (int lg = 0; lg < 128; lg += 4) {
#pragma unroll
        for (int dl = 0; dl < 4; ++dl) {
            int l = l0 + lg + dl;
            const float* Wl = W + (size_t)l * (N_AA * NCOL) + c;
#pragma unroll
            for (int s = 0; s < 4; ++s) {
                int idx = Xs[(sg * 4 + s) * 128 + lg + dl];
                idx = __builtin_amdgcn_readfirstlane(idx);   // wave-uniform
                const float2 v = *(const float2*)(Wl + (size_t)idx * NCOL);
                acc[s][0] += v.x;
                acc[s][1] += v.y;
            }
        }
    }
#pragma unroll
    for (int s = 0; s < 4; ++s) {
        float* dst = E + (size_t)(n0 + sg * 4 + s) * NCOL + c;
        atomicAdd(dst + 0, acc[s][0]);
        atomicAdd(dst + 1, acc[s][1]);
    }
}

// ---------------- kernel 4: T[n] = E[n] @ E[n]^T  (21x21) ----------------
__global__ __launch_bounds__(256) void t_kernel(const float* E, float* T) {
    __shared__ float Es[NCOL];
    int t = threadIdx.x, n = blockIdx.x;
    for (int e = t; e < NCOL; e += 256) Es[e] = E[(size_t)n * NCOL + e];
    __syncthreads();
    for (int e = t; e < 441; e += 256) {
        int r = e / 21, c = e - r * 21;
        const float* ar = &Es[r * DDIM];
        const float* br = &Es[c * DDIM];
        float s = 0.f;
#pragma unroll 4
        for (int d = 0; d < DDIM; ++d) s += ar[d] * br[d];
        T[(size_t)n * TSTRIDE + e] = s;
    }
}

// ---------------- kernel 5: kinv[n] = 1/sqrt(d^T w d), d_l = T[n][x_l, x_l] ----------------
__global__ __launch_bounds__(256) void k_kernel(const uint8_t* X8, const float* T, const float* w32, float* kinv) {
    __shared__ __align__(16) float dvec[512];
    __shared__ float Td[21];
    __shared__ float red[256];
    int t = threadIdx.x, n = blockIdx.x;
    if (t < 21) Td[t] = T[(size_t)n * TSTRIDE + t * 21 + t];
    __syncthreads();
    for (int l = t; l < 512; l += 256) dvec[l] = Td[X8[(size_t)n * 512 + l]];
    __syncthreads();
    float partial = 0.f;
    for (int p = t; p < 512; p += 256) {
        const float4* wr4 = (const float4*)(w32 + (size_t)p * 512);
        const float4* dv4 = (const float4*)dvec;
        float dot = 0.f;
        for (int q = 0; q < 128; ++q) {
            float4 wv = wr4[q];
            float4 dv = dv4[q];
            dot += wv.x * dv.x + wv.y * dv.y + wv.z * dv.z + wv.w * dv.w;
        }
        partial += dvec[p] * dot;
    }
    red[t] = partial;
    __syncthreads();
    for (int s = 128; s > 0; s >>= 1) {
        if (t < s) red[t] += red[t + s];
        __syncthreads();
    }
    if (t == 0) kinv[n] = 1.0f / sqrtf(red[0]);
}

// ---------------- kernel 6: main pair GEMM (32x32x16 MFMA, barrier-free K-loop) --------
// Tile: 4 i's x 8 j's = 32 pairs per block. grid (64, 32), 256 threads = 4 waves.
// S[pair][p] = bf16( 0.5*(T1[i][a,b] + T2[j][a,b]) ), a=X1[i,p], b=X2[j,p]
// Y = S @ w via mfma_f32_32x32x16_bf16. A (M=32 pairs) from LDS; B fragments
// loaded DIRECTLY from global wb16 using w's symmetry (B[k][n] = w[n][k] ->
// row-major b128 loads), so the K-loop has NO barriers and no LDS staging.
// Each wave owns 128 of the 512 n-columns. Fused epilogue:
// K[pair] = sum_n Y[pair,n]*S[pair,n]; out = a^2 * K * kinv_i * kinv_j.
__global__ __launch_bounds__(256) void k4_kernel(const uint8_t* X8, const float* T,
                                                 const unsigned short* wb16, const float* kinv,
                                                 const float* Ainp, float* out) {
    __shared__ unsigned short Sh[32 * 520];   // 33280 B
    __shared__ unsigned short Ts1[4 * 441];
    __shared__ unsigned short Ts2[8 * 441];
    __shared__ uint8_t Xs1[4 * 512];
    __shared__ uint8_t Xs2[8 * 512];
    __shared__ float Kacc[4][32];

    int t = threadIdx.x;
    int i0 = blockIdx.x * 4;
    int j0 = blockIdx.y * 8;

    // stage X rows
    {
        const uint32_t* s1 = (const uint32_t*)(X8 + (size_t)i0 * 512);
        uint32_t* d1 = (uint32_t*)Xs1;
        for (int e = t; e < 512; e += 256) d1[e] = s1[e];
        const uint32_t* s2 = (const uint32_t*)(X8 + (size_t)(256 + j0) * 512);
        uint32_t* d2 = (uint32_t*)Xs2;
        for (int e = t; e < 1024; e += 256) d2[e] = s2[e];
    }
    // stage T tables (bf16)
    for (int e = t; e < 4 * 441; e += 256) {
        int r = e / 441, c = e - r * 441;
        Ts1[e] = f2b(T[(size_t)(i0 + r) * TSTRIDE + c]);
    }
    for (int e = t; e < 8 * 441; e += 256) {
        int r = e / 441, c = e - r * 441;
        Ts2[e] = f2b(T[(size_t)(256 + j0 + r) * TSTRIDE + c]);
    }
    __syncthreads();

    // build S tile: 32 pairs x 512 positions
    for (int e = t; e < 32 * 512; e += 256) {
        int pr = e >> 9, p = e & 511;
        int ti = pr >> 3, tj = pr & 7;
        int a = Xs1[ti * 512 + p];
        int b = Xs2[tj * 512 + p];
        float v = 0.5f * (b2f(Ts1[ti * 441 + a * 21 + b]) + b2f(Ts2[tj * 441 + a * 21 + b]));
        Sh[pr * 520 + p] = f2b(v);
    }
    __syncthreads();

    int wid = t >> 6, lane = t & 63;
    int lr = lane & 31, hf = lane >> 5;
    int n_base = wid * 128;

    const unsigned short* Sa = &Sh[lr * 520 + hf * 8];
    const unsigned short* Bp0 = wb16 + (size_t)(n_base +  0 + lr) * 512 + hf * 8;
    const unsigned short* Bp1 = wb16 + (size_t)(n_base + 32 + lr) * 512 + hf * 8;
    const unsigned short* Bp2 = wb16 + (size_t)(n_base + 64 + lr) * 512 + hf * 8;
    const unsigned short* Bp3 = wb16 + (size_t)(n_base + 96 + lr) * 512 + hf * 8;

    f32x16 acc0, acc1, acc2, acc3;
#pragma unroll
    for (int j = 0; j < 16; ++j) { acc0[j] = 0.f; acc1[j] = 0.f; acc2[j] = 0.f; acc3[j] = 0.f; }

#pragma unroll 2
    for (int kt = 0; kt < 32; ++kt) {
        bf16x8 av = *(const bf16x8*)(Sa + kt * 16);
        bf16x8 bv0 = *(const bf16x8*)(Bp0 + kt * 16);
        bf16x8 bv1 = *(const bf16x8*)(Bp1 + kt * 16);
        bf16x8 bv2 = *(const bf16x8*)(Bp2 + kt * 16);
        bf16x8 bv3 = *(const bf16x8*)(Bp3 + kt * 16);
        acc0 = __builtin_amdgcn_mfma_f32_32x32x16_bf16(av, bv0, acc0, 0, 0, 0);
        acc1 = __builtin_amdgcn_mfma_f32_32x32x16_bf16(av, bv1, acc1, 0, 0, 0);
        acc2 = __builtin_amdgcn_mfma_f32_32x32x16_bf16(av, bv2, acc2, 0, 0, 0);
        acc3 = __builtin_amdgcn_mfma_f32_32x32x16_bf16(av, bv3, acc3, 0, 0, 0);
    }

    // fused epilogue: prow[r] = sum over this wave's 128 n of Y[row,n]*S[row,n]
    float prow[16];
#pragma unroll
    for (int r = 0; r < 16; ++r) prow[r] = 0.f;
#pragma unroll
    for (int r = 0; r < 16; ++r) {
        int row = (r & 3) + 8 * (r >> 2) + 4 * hf;   // C/D layout 32x32 (m74/m101)
        prow[r] += acc0[r] * b2f(Sh[row * 520 + (n_base +  0 + lr)]);
        prow[r] += acc1[r] * b2f(Sh[row * 520 + (n_base + 32 + lr)]);
        prow[r] += acc2[r] * b2f(Sh[row * 520 + (n_base + 64 + lr)]);
        prow[r] += acc3[r] * b2f(Sh[row * 520 + (n_base + 96 + lr)]);
    }
#pragma unroll
    for (int r = 0; r < 16; ++r) {
        float v = prow[r];
        v += __shfl_xor(v, 1);
        v += __shfl_xor(v, 2);
        v += __shfl_xor(v, 4);
        v += __shfl_xor(v, 8);
        v += __shfl_xor(v, 16);
        if (lr == 0) {
            int row = (r & 3) + 8 * (r >> 2) + 4 * hf;
            Kacc[wid][row] = v;   // each wave writes its own slice, every row once
        }
    }
    __syncthreads();

    if (t < 32) {
        float K = Kacc[0][t] + Kacc[1][t] + Kacc[2][t] + Kacc[3][t];
        int ti = t >> 3, tj = t & 7;
        int i = i0 + ti, j = j0 + tj;
        float a0 = Ainp[0];
        out[i * 256 + j] = a0 * a0 * K * kinv[i] * kinv[256 + j];
    }
}

// ---------------- launcher ----------------
extern "C" void kernel_launch(void* const* d_in, const int* in_sizes, int n_in,
                              void* d_out, int out_size, void* d_ws, size_t ws_size,
                              hipStream_t stream) {
    const int*   X1 = (const int*)d_in[0];
    const int*   X2 = (const int*)d_in[1];
    const float* W  = (const float*)d_in[2];
    const float* b  = (const float*)d_in[3];
    const float* wp = (const float*)d_in[4];
    const float* a  = (const float*)d_in[5];
    float* out = (float*)d_out;

    char* ws = (char*)d_ws;
    float*          E    = (float*)(ws + 0);            // 512*2688*4    = 5,505,024
    float*          T    = (float*)(ws + 5505024);      // 512*448*4     =   917,504
    float*          w32  = (float*)(ws + 6422528);      // 512*512*4     = 1,048,576
    unsigned short* wb16 = (unsigned short*)(ws + 7471104); // 512*512*2 =   524,288
    float*          kinv = (float*)(ws + 7995392);      // 512*4         =     2,048
    uint8_t*        X8   = (uint8_t*)(ws + 7997440);    // 512*512       =   262,144

    repack_kernel<<<1024, 256, 0, stream>>>(X1, X2, X8);
    w_build_kernel<<<1024, 256, 0, stream>>>(wp, w32, wb16);
    e_init_kernel<<<5376, 256, 0, stream>>>(b, E);
    e_gather_kernel<<<dim3(21, 32, 4), 256, 0, stream>>>(X8, W, E);
    t_kernel<<<512, 256, 0, stream>>>(E, T);
    k_kernel<<<512, 256, 0, stream>>>(X8, T, w32, kinv);
    k4_kernel<<<dim3(64, 32), 256, 0, stream>>>(X8, T, wb16, kinv, a, out);
}

// Round 3
// 439.498 us; speedup vs baseline: 1.6110x; 1.4507x over previous
//
#include <hip/hip_runtime.h>
#include <cstdint>
#include <cstddef>

// ---------------- types / helpers ----------------
typedef __attribute__((ext_vector_type(8))) __bf16 bf16x8;
typedef __attribute__((ext_vector_type(4))) float f32x4;
typedef __attribute__((ext_vector_type(16))) float f32x16;

__device__ __forceinline__ unsigned short f2b(float x) {
    uint32_t u = __float_as_uint(x);
    u += 0x7FFFu + ((u >> 16) & 1u);   // RNE
    return (unsigned short)(u >> 16);
}
__device__ __forceinline__ float b2f(unsigned short h) {
    return __uint_as_float(((uint32_t)h) << 16);
}

#define L_SEQ 512
#define N_AA 21
#define DDIM 128
#define NCOL 2688        // 21*128
#define NSEQ 512         // 256 + 256
#define TSTRIDE 448      // padded 441
#define KTOT 10752       // 512*21
#define KWORDS_TOT 336   // 10752/32
#define KCHUNK 896       // 10752/12
#define KWORDS 28        // 896/32

// ---------------- kernel 1: repack X int32 -> u8, combined [512][512] ----------------
__global__ __launch_bounds__(256) void repack_kernel(const int* X1, const int* X2, uint8_t* X8) {
    int e = blockIdx.x * 256 + threadIdx.x;   // 262144 total
    if (e < 131072) X8[e] = (uint8_t)X1[e];
    else            X8[e] = (uint8_t)X2[e - 131072];
}

// ---------------- kernel 1b: one-hot bitmask Abits[seq][word], bit (l*21+aa - 32w) ----
__global__ __launch_bounds__(256) void abits_kernel(const uint8_t* X8, uint32_t* Abits) {
    int e = blockIdx.x * 256 + threadIdx.x;   // 512*336 = 172032
    if (e >= NSEQ * KWORDS_TOT) return;
    int seq = e / KWORDS_TOT, w = e - seq * KWORDS_TOT;
    int k0 = w * 32;
    int l_lo = k0 / N_AA;
    int l_hi = (k0 + 31) / N_AA;
    if (l_hi > L_SEQ - 1) l_hi = L_SEQ - 1;
    uint32_t bits = 0;
    for (int l = l_lo; l <= l_hi; ++l) {
        int aa = X8[(size_t)seq * L_SEQ + l];
        int pos = l * N_AA + aa - k0;
        if (pos >= 0 && pos < 32) bits |= (1u << pos);
    }
    Abits[e] = bits;
}

// ---------------- kernel 2: w = sigmoid(wm) -> w32 (row-major) + wswz (MFMA-frag order)
// wswz tile (nb,kb) covers n in [32nb,32nb+32), k in [16kb,16kb+16); element for
// lane (hf,lr), j stored at ((nb*32+kb)*512 + lane*8 + j). B[k][n] = w[n][k] (symmetric).
__global__ __launch_bounds__(256) void w_build_kernel(const float* wp, float* w32, unsigned short* wswz) {
    int e = blockIdx.x * 256 + threadIdx.x;   // 262144 = 512*512
    int p = e >> 9, q = e & 511;
    float x = 0.0f;
    if (p > q)      x = wp[p * (p - 1) / 2 + q];
    else if (p < q) x = wp[q * (q - 1) / 2 + p];
    float s = 1.0f / (1.0f + expf(-x));
    w32[e] = s;
    // store w[p][q] at B-frag position (k=q, n=p)
    int nb = p >> 5, lr = p & 31;
    int kb = q >> 4, hf = (q >> 3) & 1, j = q & 7;
    wswz[(size_t)((nb * 32 + kb) * 512) + (hf * 32 + lr) * 8 + j] = f2b(s);
}

// ---------------- kernel 3a: E init with bias ----------------
__global__ __launch_bounds__(256) void e_init_kernel(const float* bvec, float* E) {
    int e = blockIdx.x * 256 + threadIdx.x;   // 512*2688 = 1376256
    int c = e % NCOL;
    E[e] = bvec[c];
}

// ---------------- kernel 3b: E += OneHot @ W via MFMA, hi/lo bf16 split of W --------
// grid (21 n-tiles of 128, 2 m-tiles of 256, 12 k-chunks of 896). 256 thr = 4 waves.
// Wave (wid): m-half (wid&1)*128 (4 sub-tiles of 32), n-half (wid>>1)*64 (2 sub of 32).
// A one-hot built in regs from Abits (LDS-staged). B = W columns, coalesced fp32
// loads converted to bf16 hi+lo (exact to 2^-17). fp32 atomicAdd epilogue.
__global__ __launch_bounds__(256, 2) void e_mfma_kernel(const uint32_t* Abits, const float* W, float* E) {
    __shared__ uint32_t Ab[256 * 29];
    int t = threadIdx.x;
    int c0 = blockIdx.x * 128;
    int m0 = blockIdx.y * 256;
    int w0 = blockIdx.z * KWORDS;

    for (int idx = t; idx < 256 * KWORDS; idx += 256) {
        int r = idx / KWORDS, w = idx - r * KWORDS;
        Ab[r * 29 + w] = Abits[(size_t)(m0 + r) * KWORDS_TOT + w0 + w];
    }
    __syncthreads();

    int wid = t >> 6, lane = t & 63;
    int lr = lane & 31, hf = lane >> 5;
    int mbase = (wid & 1) * 128;
    int nbase = (wid >> 1) * 64;

    f32x16 acc[4][2];
#pragma unroll
    for (int s = 0; s < 4; ++s)
#pragma unroll
        for (int o = 0; o < 2; ++o)
#pragma unroll
            for (int r = 0; r < 16; ++r) acc[s][o][r] = 0.f;

    int kglob0 = blockIdx.z * KCHUNK;
    const float* Wp = W + (size_t)(kglob0 + hf * 8) * NCOL + c0 + nbase + lr;

    for (int ks = 0; ks < KCHUNK / 16; ++ks) {
        // ---- A fragments (one-hot from bitmask) ----
        int word = ks >> 1;
        int b0 = (ks & 1) * 16 + hf * 8;
        bf16x8 afrag[4];
#pragma unroll
        for (int s = 0; s < 4; ++s) {
            uint32_t bits = Ab[(mbase + s * 32 + lr) * 29 + word];
            uint32_t bb = (bits >> b0) & 0xFFu;
            union { bf16x8 v; uint32_t u[4]; } af;
#pragma unroll
            for (int p = 0; p < 4; ++p) {
                uint32_t u = 0;
                if ((bb >> (2 * p)) & 1u)     u |= 0x3F80u;
                if ((bb >> (2 * p + 1)) & 1u) u |= 0x3F800000u;
                af.u[p] = u;
            }
            afrag[s] = af.v;
        }
        // ---- B fragments: 2 n-subtiles, hi/lo ----
#pragma unroll
        for (int o = 0; o < 2; ++o) {
            const float* wp_ = Wp + o * 32;
            float f[8];
#pragma unroll
            for (int j = 0; j < 8; ++j) f[j] = wp_[(size_t)j * NCOL];
            union { bf16x8 v; uint32_t u[4]; } bh, bl;
#pragma unroll
            for (int p = 0; p < 4; ++p) {
                uint32_t u0 = __float_as_uint(f[2 * p]);
                uint32_t u1 = __float_as_uint(f[2 * p + 1]);
                uint32_t h0 = u0 & 0xFFFF0000u;
                uint32_t h1 = u1 & 0xFFFF0000u;
                bh.u[p] = (h0 >> 16) | h1;
                float l0 = f[2 * p]     - __uint_as_float(h0);
                float l1 = f[2 * p + 1] - __uint_as_float(h1);
                bl.u[p] = (uint32_t)f2b(l0) | ((uint32_t)f2b(l1) << 16);
            }
#pragma unroll
            for (int s = 0; s < 4; ++s)
                acc[s][o] = __builtin_amdgcn_mfma_f32_32x32x16_bf16(afrag[s], bh.v, acc[s][o], 0, 0, 0);
#pragma unroll
            for (int s = 0; s < 4; ++s)
                acc[s][o] = __builtin_amdgcn_mfma_f32_32x32x16_bf16(afrag[s], bl.v, acc[s][o], 0, 0, 0);
        }
        Wp += (size_t)16 * NCOL;
    }

    // ---- epilogue: atomic accumulate into E ----
#pragma unroll
    for (int s = 0; s < 4; ++s)
#pragma unroll
        for (int o = 0; o < 2; ++o)
#pragma unroll
            for (int r = 0; r < 16; ++r) {
                int row = (r & 3) + 8 * (r >> 2) + 4 * hf;
                float* dst = E + (size_t)(m0 + mbase + s * 32 + row) * NCOL + c0 + nbase + o * 32 + lr;
                atomicAdd(dst, acc[s][o][r]);
            }
}

// ---------------- kernel 4: T[n] = E[n] @ E[n]^T  (21x21) ----------------
__global__ __launch_bounds__(256) void t_kernel(const float* E, float* T) {
    __shared__ float Es[NCOL];
    int t = threadIdx.x, n = blockIdx.x;
    for (int e = t; e < NCOL; e += 256) Es[e] = E[(size_t)n * NCOL + e];
    __syncthreads();
    for (int e = t; e < 441; e += 256) {
        int r = e / 21, c = e - r * 21;
        const float* ar = &Es[r * DDIM];
        const float* br = &Es[c * DDIM];
        float s = 0.f;
#pragma unroll 4
        for (int d = 0; d < DDIM; ++d) s += ar[d] * br[d];
        T[(size_t)n * TSTRIDE + e] = s;
    }
}

// ---------------- kernel 5: kinv[n] = 1/sqrt(d^T w d), d_l = T[n][x_l, x_l] ----------
__global__ __launch_bounds__(256) void k_kernel(const uint8_t* X8, const float* T, const float* w32, float* kinv) {
    __shared__ __align__(16) float dvec[512];
    __shared__ float Td[21];
    __shared__ float red[256];
    int t = threadIdx.x, n = blockIdx.x;
    if (t < 21) Td[t] = T[(size_t)n * TSTRIDE + t * 21 + t];
    __syncthreads();
    for (int l = t; l < 512; l += 256) dvec[l] = Td[X8[(size_t)n * 512 + l]];
    __syncthreads();
    float partial = 0.f;
    for (int p = t; p < 512; p += 256) {
        const float4* wr4 = (const float4*)(w32 + (size_t)p * 512);
        const float4* dv4 = (const float4*)dvec;
        float dot = 0.f;
        for (int q = 0; q < 128; ++q) {
            float4 wv = wr4[q];
            float4 dv = dv4[q];
            dot += wv.x * dv.x + wv.y * dv.y + wv.z * dv.z + wv.w * dv.w;
        }
        partial += dvec[p] * dot;
    }
    red[t] = partial;
    __syncthreads();
    for (int s = 128; s > 0; s >>= 1) {
        if (t < s) red[t] += red[t + s];
        __syncthreads();
    }
    if (t == 0) kinv[n] = 1.0f / sqrtf(red[0]);
}

// ---------------- kernel 6: main pair GEMM (32x32x16 MFMA, swizzled B) --------------
__global__ __launch_bounds__(256) void k4_kernel(const uint8_t* X8, const float* T,
                                                 const unsigned short* wswz, const float* kinv,
                                                 const float* Ainp, float* out) {
    __shared__ unsigned short Sh[32 * 520];
    __shared__ unsigned short Ts1[4 * 441];
    __shared__ unsigned short Ts2[8 * 441];
    __shared__ uint8_t Xs1[4 * 512];
    __shared__ uint8_t Xs2[8 * 512];
    __shared__ float Kacc[4][32];

    int t = threadIdx.x;
    int i0 = blockIdx.x * 4;
    int j0 = blockIdx.y * 8;

    {
        const uint32_t* s1 = (const uint32_t*)(X8 + (size_t)i0 * 512);
        uint32_t* d1 = (uint32_t*)Xs1;
        for (int e = t; e < 512; e += 256) d1[e] = s1[e];
        const uint32_t* s2 = (const uint32_t*)(X8 + (size_t)(256 + j0) * 512);
        uint32_t* d2 = (uint32_t*)Xs2;
        for (int e = t; e < 1024; e += 256) d2[e] = s2[e];
    }
    for (int e = t; e < 4 * 441; e += 256) {
        int r = e / 441, c = e - r * 441;
        Ts1[e] = f2b(T[(size_t)(i0 + r) * TSTRIDE + c]);
    }
    for (int e = t; e < 8 * 441; e += 256) {
        int r = e / 441, c = e - r * 441;
        Ts2[e] = f2b(T[(size_t)(256 + j0 + r) * TSTRIDE + c]);
    }
    __syncthreads();

    for (int e = t; e < 32 * 512; e += 256) {
        int pr = e >> 9, p = e & 511;
        int ti = pr >> 3, tj = pr & 7;
        int a = Xs1[ti * 512 + p];
        int b = Xs2[tj * 512 + p];
        float v = 0.5f * (b2f(Ts1[ti * 441 + a * 21 + b]) + b2f(Ts2[tj * 441 + a * 21 + b]));
        Sh[pr * 520 + p] = f2b(v);
    }
    __syncthreads();

    int wid = t >> 6, lane = t & 63;
    int lr = lane & 31, hf = lane >> 5;
    int n_base = wid * 128;

    const unsigned short* Sa = &Sh[lr * 520 + hf * 8];
    // swizzled B: tile (nb = wid*4+o, kb = kt) at ((nb*32+kb)*512 + lane*8)
    const unsigned short* Bz0 = wswz + (size_t)((wid * 4 + 0) * 32) * 512 + lane * 8;
    const unsigned short* Bz1 = wswz + (size_t)((wid * 4 + 1) * 32) * 512 + lane * 8;
    const unsigned short* Bz2 = wswz + (size_t)((wid * 4 + 2) * 32) * 512 + lane * 8;
    const unsigned short* Bz3 = wswz + (size_t)((wid * 4 + 3) * 32) * 512 + lane * 8;

    f32x16 acc0, acc1, acc2, acc3;
#pragma unroll
    for (int j = 0; j < 16; ++j) { acc0[j] = 0.f; acc1[j] = 0.f; acc2[j] = 0.f; acc3[j] = 0.f; }

#pragma unroll 2
    for (int kt = 0; kt < 32; ++kt) {
        bf16x8 av = *(const bf16x8*)(Sa + kt * 16);
        bf16x8 bv0 = *(const bf16x8*)(Bz0 + kt * 512);
        bf16x8 bv1 = *(const bf16x8*)(Bz1 + kt * 512);
        bf16x8 bv2 = *(const bf16x8*)(Bz2 + kt * 512);
        bf16x8 bv3 = *(const bf16x8*)(Bz3 + kt * 512);
        acc0 = __builtin_amdgcn_mfma_f32_32x32x16_bf16(av, bv0, acc0, 0, 0, 0);
        acc1 = __builtin_amdgcn_mfma_f32_32x32x16_bf16(av, bv1, acc1, 0, 0, 0);
        acc2 = __builtin_amdgcn_mfma_f32_32x32x16_bf16(av, bv2, acc2, 0, 0, 0);
        acc3 = __builtin_amdgcn_mfma_f32_32x32x16_bf16(av, bv3, acc3, 0, 0, 0);
    }

    float prow[16];
#pragma unroll
    for (int r = 0; r < 16; ++r) prow[r] = 0.f;
#pragma unroll
    for (int r = 0; r < 16; ++r) {
        int row = (r & 3) + 8 * (r >> 2) + 4 * hf;
        prow[r] += acc0[r] * b2f(Sh[row * 520 + (n_base +  0 + lr)]);
        prow[r] += acc1[r] * b2f(Sh[row * 520 + (n_base + 32 + lr)]);
        prow[r] += acc2[r] * b2f(Sh[row * 520 + (n_base + 64 + lr)]);
        prow[r] += acc3[r] * b2f(Sh[row * 520 + (n_base + 96 + lr)]);
    }
#pragma unroll
    for (int r = 0; r < 16; ++r) {
        float v = prow[r];
        v += __shfl_xor(v, 1);
        v += __shfl_xor(v, 2);
        v += __shfl_xor(v, 4);
        v += __shfl_xor(v, 8);
        v += __shfl_xor(v, 16);
        if (lr == 0) {
            int row = (r & 3) + 8 * (r >> 2) + 4 * hf;
            Kacc[wid][row] = v;
        }
    }
    __syncthreads();

    if (t < 32) {
        float K = Kacc[0][t] + Kacc[1][t] + Kacc[2][t] + Kacc[3][t];
        int ti = t >> 3, tj = t & 7;
        int i = i0 + ti, j = j0 + tj;
        float a0 = Ainp[0];
        out[i * 256 + j] = a0 * a0 * K * kinv[i] * kinv[256 + j];
    }
}

// ---------------- launcher ----------------
extern "C" void kernel_launch(void* const* d_in, const int* in_sizes, int n_in,
                              void* d_out, int out_size, void* d_ws, size_t ws_size,
                              hipStream_t stream) {
    const int*   X1 = (const int*)d_in[0];
    const int*   X2 = (const int*)d_in[1];
    const float* W  = (const float*)d_in[2];
    const float* b  = (const float*)d_in[3];
    const float* wp = (const float*)d_in[4];
    const float* a  = (const float*)d_in[5];
    float* out = (float*)d_out;

    char* ws = (char*)d_ws;
    float*          E     = (float*)(ws + 0);                 // 5,505,024
    float*          T     = (float*)(ws + 5505024);           //   917,504
    float*          w32   = (float*)(ws + 6422528);           // 1,048,576
    unsigned short* wswz  = (unsigned short*)(ws + 7471104);  //   524,288
    float*          kinv  = (float*)(ws + 7995392);           //     2,048
    uint8_t*        X8    = (uint8_t*)(ws + 7997440);         //   262,144
    uint32_t*       Abits = (uint32_t*)(ws + 8259584);        //   688,128  (end 8,947,712)

    repack_kernel<<<1024, 256, 0, stream>>>(X1, X2, X8);
    abits_kernel<<<672, 256, 0, stream>>>(X8, Abits);
    w_build_kernel<<<1024, 256, 0, stream>>>(wp, w32, wswz);
    e_init_kernel<<<5376, 256, 0, stream>>>(b, E);
    e_mfma_kernel<<<dim3(21, 2, 12), 256, 0, stream>>>(Abits, W, E);
    t_kernel<<<512, 256, 0, stream>>>(E, T);
    k_kernel<<<512, 256, 0, stream>>>(X8, T, w32, kinv);
    k4_kernel<<<dim3(64, 32), 256, 0, stream>>>(X8, T, wswz, kinv, a, out);
}